// Round 1
// baseline (2273.795 us; speedup 1.0000x reference)
//
#include <hip/hip_runtime.h>

// ---------------- problem constants ----------------
// x:[N,128] W1:[128,128] b1:[128] W2:[128,64] b2:[64] edge_index:[2,E]
// out:[N,64] fp32

// ---------------- workspace layout (bytes) ----------------
static constexpr size_t OFF_DEG  = 0;                       // u32[N]      (400,000 B)
static constexpr size_t OFF_DINV = 524288;                  // f32[N]
static constexpr size_t OFF_SRC  = 1048576;                 // i32[E]  (6.4 MB)
static constexpr size_t OFF_DST  = OFF_SRC + 6400000;       // i32[E]
static constexpr size_t OFF_FLAG = OFF_DST + 6400000;       // u32[1]
static constexpr size_t OFF_BUFA = 14680064;                // f32[N*128] (51.2 MB)
static constexpr size_t OFF_BUFB = OFF_BUFA + 51200000;     // f32[N*128] (51.2 MB)

// ---------------- edge dtype detection ----------------
// If edge_index is int64: words[2i+1] (high words of first values) are all 0.
// If int32: those words are random node ids, ~all nonzero. Check 4096 of them.
__global__ void detect_kernel(const unsigned* __restrict__ w,
                              unsigned* __restrict__ flag) {
    int i = blockIdx.x * blockDim.x + threadIdx.x;   // 4096 threads
    if (w[2 * i + 1] != 0u) atomicOr(flag, 1u);
}

__global__ void convert_kernel(const unsigned* __restrict__ w,
                               const unsigned* __restrict__ flag,
                               int* __restrict__ src, int* __restrict__ dst,
                               int E) {
    int i = blockIdx.x * blockDim.x + threadIdx.x;
    if (i >= E) return;
    if (*flag) {            // int32 layout: [src[E], dst[E]]
        src[i] = (int)w[i];
        dst[i] = (int)w[E + i];
    } else {                // int64 layout: low word of element j at word 2j
        src[i] = (int)w[2 * i];
        dst[i] = (int)w[2 * E + 2 * i];
    }
}

// ---------------- degree / dinv ----------------
__global__ void deg_kernel(const int* __restrict__ dst,
                           unsigned* __restrict__ deg, int E) {
    int i = blockIdx.x * blockDim.x + threadIdx.x;
    if (i < E) atomicAdd(&deg[dst[i]], 1u);
}

__global__ void dinv_kernel(const unsigned* __restrict__ deg,
                            float* __restrict__ dinv, int N) {
    int i = blockIdx.x * blockDim.x + threadIdx.x;
    if (i < N) dinv[i] = rsqrtf((float)deg[i] + 1.0f);
}

// ---------------- fp32 GEMM, out = (A @ B) * dinv[row] ----------------
// A:[M,128] B:[128,BN] out:[M,BN].  Tile: 128 rows x BN cols, KT=32 staging.
// Thread (tx,ty) in 16x16: rows ty+16*i (i<8), cols {tx*4..+3} (+64 if BN=128).
template <int BN>
__global__ __launch_bounds__(256) void gemm_scale(
    const float* __restrict__ A, const float* __restrict__ B,
    const float* __restrict__ dinv, float* __restrict__ out, int M) {
    constexpr int K = 128, BM = 128, KT = 32;
    constexpr int LDA = KT + 4;   // 36 floats: row starts 4 banks apart
    constexpr int LDB = BN + 4;   // 132 floats
    constexpr int NCH = BN / 64;  // float4 col-chunks per thread (2 or 1)
    __shared__ float sA[BM * LDA];
    __shared__ float sB[KT * LDB];

    const int t = threadIdx.x;
    const int row0 = blockIdx.x * BM;
    const int tx = t & 15, ty = t >> 4;

    float4 acc[8][NCH];
#pragma unroll
    for (int i = 0; i < 8; i++)
#pragma unroll
        for (int ch = 0; ch < NCH; ch++) acc[i][ch] = make_float4(0.f, 0.f, 0.f, 0.f);

    for (int kt = 0; kt < K; kt += KT) {
        // stage A chunk: BM x KT
        for (int idx = t * 4; idx < BM * KT; idx += 1024) {
            int r = idx / KT, k = idx - r * KT;
            float4 v = make_float4(0.f, 0.f, 0.f, 0.f);
            int row = row0 + r;
            if (row < M) v = *(const float4*)(A + (size_t)row * K + kt + k);
            float* p = sA + r * LDA + k;
            p[0] = v.x; p[1] = v.y; p[2] = v.z; p[3] = v.w;
        }
        // stage B chunk: KT x BN
        for (int idx = t * 4; idx < KT * BN; idx += 1024) {
            int k = idx / BN, c = idx - k * BN;
            float4 v = *(const float4*)(B + (size_t)(kt + k) * BN + c);
            float* p = sB + k * LDB + c;
            p[0] = v.x; p[1] = v.y; p[2] = v.z; p[3] = v.w;
        }
        __syncthreads();

        for (int k = 0; k < KT; k += 4) {
            float4 a[8];
#pragma unroll
            for (int i = 0; i < 8; i++)
                a[i] = *(const float4*)(sA + (ty + 16 * i) * LDA + k);
#pragma unroll
            for (int kk = 0; kk < 4; kk++) {
                float4 b[NCH];
#pragma unroll
                for (int ch = 0; ch < NCH; ch++)
                    b[ch] = *(const float4*)(sB + (k + kk) * LDB + ch * 64 + tx * 4);
#pragma unroll
                for (int i = 0; i < 8; i++) {
                    float av = (kk == 0) ? a[i].x : (kk == 1) ? a[i].y
                             : (kk == 2) ? a[i].z : a[i].w;
#pragma unroll
                    for (int ch = 0; ch < NCH; ch++) {
                        acc[i][ch].x += av * b[ch].x;
                        acc[i][ch].y += av * b[ch].y;
                        acc[i][ch].z += av * b[ch].z;
                        acc[i][ch].w += av * b[ch].w;
                    }
                }
            }
        }
        __syncthreads();
    }

#pragma unroll
    for (int i = 0; i < 8; i++) {
        int row = row0 + ty + 16 * i;
        if (row < M) {
            float s = dinv[row];
#pragma unroll
            for (int ch = 0; ch < NCH; ch++) {
                float4 v = acc[i][ch];
                v.x *= s; v.y *= s; v.z *= s; v.w *= s;
                *(float4*)(out + (size_t)row * BN + ch * 64 + tx * 4) = v;
            }
        }
    }
}

// ---------------- edge scatter: acc[dst] += hs[src] ----------------
// One wave handles 128 channels worth of edge-work: C=128 -> 1 edge/wave,
// C=64 -> 2 edges/wave. Row gathers are fully coalesced (contiguous rows).
template <int C>
__global__ __launch_bounds__(256) void scatter_kernel(
    const int* __restrict__ src, const int* __restrict__ dst,
    const float* __restrict__ hs, float* __restrict__ acc, int E) {
    constexpr int EPW = 128 / C;  // edges per wave
    const int wave = blockIdx.x * 4 + (threadIdx.x >> 6);
    const int lane = threadIdx.x & 63;
    const int sub = lane / (C / 2);
    const int l = lane - sub * (C / 2);
    const int e = wave * EPW + sub;
    if (e >= E) return;
    const int s = src[e], d = dst[e];
    const float2 v = *(const float2*)(hs + (size_t)s * C + l * 2);
    float* p = acc + (size_t)d * C + l * 2;
    unsafeAtomicAdd(p, v.x);
    unsafeAtomicAdd(p + 1, v.y);
}

// ---------------- combine: out = (acc + hs) * dinv + b, optional ReLU ------
template <int C, bool RELU>
__global__ __launch_bounds__(256) void combine_kernel(
    const float* __restrict__ acc, const float* __restrict__ hs,
    const float* __restrict__ dinv, const float* __restrict__ bias,
    float* __restrict__ out, int N) {
    constexpr int C4 = C / 4;
    int idx = blockIdx.x * blockDim.x + threadIdx.x;  // float4 index
    if (idx >= N * C4) return;
    int i = idx / C4;
    int c4 = idx - i * C4;
    float s = dinv[i];
    float4 a = *(const float4*)(acc + (size_t)idx * 4);
    float4 h = *(const float4*)(hs + (size_t)idx * 4);
    float4 b = *(const float4*)(bias + c4 * 4);
    float4 o;
    o.x = (a.x + h.x) * s + b.x;
    o.y = (a.y + h.y) * s + b.y;
    o.z = (a.z + h.z) * s + b.z;
    o.w = (a.w + h.w) * s + b.w;
    if (RELU) {
        o.x = fmaxf(o.x, 0.f); o.y = fmaxf(o.y, 0.f);
        o.z = fmaxf(o.z, 0.f); o.w = fmaxf(o.w, 0.f);
    }
    *(float4*)(out + (size_t)idx * 4) = o;
}

// ---------------- launch ----------------
extern "C" void kernel_launch(void* const* d_in, const int* in_sizes, int n_in,
                              void* d_out, int out_size, void* d_ws,
                              size_t ws_size, hipStream_t stream) {
    const float* x  = (const float*)d_in[0];
    const float* W1 = (const float*)d_in[1];
    const float* b1 = (const float*)d_in[2];
    const float* W2 = (const float*)d_in[3];
    const float* b2 = (const float*)d_in[4];
    const unsigned* ew = (const unsigned*)d_in[5];
    const int E = in_sizes[5] / 2;      // 1,600,000
    const int N = in_sizes[0] / 128;    // 100,000

    char* ws = (char*)d_ws;
    unsigned* deg  = (unsigned*)(ws + OFF_DEG);
    float* dinv    = (float*)(ws + OFF_DINV);
    int* src32     = (int*)(ws + OFF_SRC);
    int* dst32     = (int*)(ws + OFF_DST);
    unsigned* flag = (unsigned*)(ws + OFF_FLAG);
    float* bufA    = (float*)(ws + OFF_BUFA);   // hs1 -> relu(out1) -> acc2
    float* bufB    = (float*)(ws + OFF_BUFB);   // acc1 -> hs2

    hipMemsetAsync(flag, 0, 4, stream);
    hipMemsetAsync(deg, 0, (size_t)N * 4, stream);
    hipMemsetAsync(bufB, 0, (size_t)N * 128 * 4, stream);  // acc1 = 0

    detect_kernel<<<16, 256, 0, stream>>>(ew, flag);
    convert_kernel<<<(E + 255) / 256, 256, 0, stream>>>(ew, flag, src32, dst32, E);
    deg_kernel<<<(E + 255) / 256, 256, 0, stream>>>(dst32, deg, E);
    dinv_kernel<<<(N + 255) / 256, 256, 0, stream>>>(deg, dinv, N);

    // ---- layer 1 (C=128) ----
    gemm_scale<128><<<(N + 127) / 128, 256, 0, stream>>>(x, W1, dinv, bufA, N);
    scatter_kernel<128><<<(E + 3) / 4, 256, 0, stream>>>(src32, dst32, bufA, bufB, E);
    combine_kernel<128, true><<<(N * 32 + 255) / 256, 256, 0, stream>>>(
        bufB, bufA, dinv, b1, bufA, N);   // in-place relu(out1) into bufA

    // ---- layer 2 (C=64) ----
    gemm_scale<64><<<(N + 127) / 128, 256, 0, stream>>>(bufA, W2, dinv, bufB, N);
    hipMemsetAsync(bufA, 0, (size_t)N * 64 * 4, stream);   // acc2 = 0
    scatter_kernel<64><<<(E + 7) / 8, 256, 0, stream>>>(src32, dst32, bufB, bufA, E);
    combine_kernel<64, false><<<(N * 16 + 255) / 256, 256, 0, stream>>>(
        bufA, bufB, dinv, b2, (float*)d_out, N);
}

// Round 2
// 602.336 us; speedup vs baseline: 3.7750x; 3.7750x over previous
//
#include <hip/hip_runtime.h>

// ---------------- problem constants ----------------
// x:[N,128] W1:[128,128] b1:[128] W2:[128,64] b2:[64] edge_index:[2,E]
// out:[N,64] fp32

// ---------------- workspace layout (bytes) ----------------
static constexpr size_t OFF_FLAG = 0;                       // u32[1]
static constexpr size_t OFF_DEG  = 256;                     // u32[N]
static constexpr size_t OFF_ROW  = 458752;                  // i32[N+1]
static constexpr size_t OFF_CUR  = 917504;                  // u32[N]
static constexpr size_t OFF_BSUM = 1376256;                 // u32[1024]
static constexpr size_t OFF_DINV = 1441792;                 // f32[N]
static constexpr size_t OFF_CSR  = 1900544;                 // i32[E]
static constexpr size_t OFF_BUFA = 8388608;                 // f32[N*128] (51.2 MB)
static constexpr size_t OFF_BUFB = 59768832;                // f32[N*128] (51.2 MB)

// ---------------- edge dtype detection ----------------
// int64 layout: high word of first 2048 elements all zero. int32: random ids.
__global__ void detect_kernel(const unsigned* __restrict__ w,
                              unsigned* __restrict__ flag) {
    int i = blockIdx.x * blockDim.x + threadIdx.x;   // 4096 threads
    if (w[2 * i + 1] != 0u) atomicOr(flag, 1u);
}

__device__ __forceinline__ int edge_dst(const unsigned* w, unsigned flag,
                                        int e, int E) {
    return flag ? (int)w[E + e] : (int)w[2 * E + 2 * e];
}
__device__ __forceinline__ int edge_src(const unsigned* w, unsigned flag,
                                        int e, int E) {
    return flag ? (int)w[e] : (int)w[2 * e];
}

// ---------------- degree histogram over dst ----------------
__global__ void deg_kernel(const unsigned* __restrict__ w,
                           const unsigned* __restrict__ flag,
                           unsigned* __restrict__ deg, int E) {
    int e = blockIdx.x * blockDim.x + threadIdx.x;
    if (e < E) atomicAdd(&deg[edge_dst(w, *flag, e, E)], 1u);
}

// ---------------- scan: row = exclusive_scan(deg), rowstart[N] = E ----------
// scan1: per-block (1024) inclusive scan -> row[i+1] (partial), bsum[blk]=total
__global__ __launch_bounds__(1024) void scan1_kernel(
    const unsigned* __restrict__ deg, unsigned* __restrict__ row,
    unsigned* __restrict__ bsum, int N) {
    __shared__ unsigned sh[1024];
    int gid = blockIdx.x * 1024 + threadIdx.x;
    int t = threadIdx.x;
    unsigned v = (gid < N) ? deg[gid] : 0u;
    sh[t] = v;
    __syncthreads();
#pragma unroll
    for (int off = 1; off < 1024; off <<= 1) {
        unsigned add = (t >= off) ? sh[t - off] : 0u;
        __syncthreads();
        sh[t] += add;
        __syncthreads();
    }
    if (gid < N) row[gid + 1] = sh[t];
    if (t == 1023) bsum[blockIdx.x] = sh[1023];
}

// scan2: exclusive scan of bsum (NB <= 1024 entries), serial on thread 0
__global__ void scan2_kernel(unsigned* __restrict__ bsum, int NB) {
    if (threadIdx.x == 0 && blockIdx.x == 0) {
        unsigned run = 0;
        for (int b = 0; b < NB; b++) {
            unsigned t = bsum[b];
            bsum[b] = run;
            run += t;
        }
    }
}

// scan3: finalize row, init cursor, compute dinv. Thread gid owns element gid+1
// of row/cursor exclusively (no races).
__global__ void scan3_kernel(unsigned* __restrict__ row,
                             const unsigned* __restrict__ bsum,
                             unsigned* __restrict__ cursor,
                             const unsigned* __restrict__ deg,
                             float* __restrict__ dinv, int N) {
    int gid = blockIdx.x * blockDim.x + threadIdx.x;
    if (gid >= N) return;
    unsigned t = row[gid + 1] + bsum[gid >> 10];
    row[gid + 1] = t;
    if (gid + 1 < N) cursor[gid + 1] = t;
    if (gid == 0) { row[0] = 0u; cursor[0] = 0u; }
    dinv[gid] = rsqrtf((float)deg[gid] + 1.0f);
}

// ---------------- bucket: csr[pos] = src, grouped by dst ----------------
__global__ void bucket_kernel(const unsigned* __restrict__ w,
                              const unsigned* __restrict__ flag,
                              unsigned* __restrict__ cursor,
                              int* __restrict__ csr, int E) {
    int e = blockIdx.x * blockDim.x + threadIdx.x;
    if (e >= E) return;
    unsigned f = *flag;
    int d = edge_dst(w, f, e, E);
    int s = edge_src(w, f, e, E);
    unsigned pos = atomicAdd(&cursor[d], 1u);
    csr[pos] = s;
}

// ---------------- fp32 GEMM, out = (A @ B) * dinv[row] ----------------
template <int BN>
__global__ __launch_bounds__(256) void gemm_scale(
    const float* __restrict__ A, const float* __restrict__ B,
    const float* __restrict__ dinv, float* __restrict__ out, int M) {
    constexpr int K = 128, BM = 128, KT = 32;
    constexpr int LDA = KT + 4;
    constexpr int LDB = BN + 4;
    constexpr int NCH = BN / 64;
    __shared__ float sA[BM * LDA];
    __shared__ float sB[KT * LDB];

    const int t = threadIdx.x;
    const int row0 = blockIdx.x * BM;
    const int tx = t & 15, ty = t >> 4;

    float4 acc[8][NCH];
#pragma unroll
    for (int i = 0; i < 8; i++)
#pragma unroll
        for (int ch = 0; ch < NCH; ch++) acc[i][ch] = make_float4(0.f, 0.f, 0.f, 0.f);

    for (int kt = 0; kt < K; kt += KT) {
        for (int idx = t * 4; idx < BM * KT; idx += 1024) {
            int r = idx / KT, k = idx - r * KT;
            float4 v = make_float4(0.f, 0.f, 0.f, 0.f);
            int row = row0 + r;
            if (row < M) v = *(const float4*)(A + (size_t)row * K + kt + k);
            float* p = sA + r * LDA + k;
            p[0] = v.x; p[1] = v.y; p[2] = v.z; p[3] = v.w;
        }
        for (int idx = t * 4; idx < KT * BN; idx += 1024) {
            int k = idx / BN, c = idx - k * BN;
            float4 v = *(const float4*)(B + (size_t)(kt + k) * BN + c);
            float* p = sB + k * LDB + c;
            p[0] = v.x; p[1] = v.y; p[2] = v.z; p[3] = v.w;
        }
        __syncthreads();

        for (int k = 0; k < KT; k += 4) {
            float4 a[8];
#pragma unroll
            for (int i = 0; i < 8; i++)
                a[i] = *(const float4*)(sA + (ty + 16 * i) * LDA + k);
#pragma unroll
            for (int kk = 0; kk < 4; kk++) {
                float4 b[NCH];
#pragma unroll
                for (int ch = 0; ch < NCH; ch++)
                    b[ch] = *(const float4*)(sB + (k + kk) * LDB + ch * 64 + tx * 4);
#pragma unroll
                for (int i = 0; i < 8; i++) {
                    float av = (kk == 0) ? a[i].x : (kk == 1) ? a[i].y
                             : (kk == 2) ? a[i].z : a[i].w;
#pragma unroll
                    for (int ch = 0; ch < NCH; ch++) {
                        acc[i][ch].x += av * b[ch].x;
                        acc[i][ch].y += av * b[ch].y;
                        acc[i][ch].z += av * b[ch].z;
                        acc[i][ch].w += av * b[ch].w;
                    }
                }
            }
        }
        __syncthreads();
    }

#pragma unroll
    for (int i = 0; i < 8; i++) {
        int row = row0 + ty + 16 * i;
        if (row < M) {
            float s = dinv[row];
#pragma unroll
            for (int ch = 0; ch < NCH; ch++) {
                float4 v = acc[i][ch];
                v.x *= s; v.y *= s; v.z *= s; v.w *= s;
                *(float4*)(out + (size_t)row * BN + ch * 64 + tx * 4) = v;
            }
        }
    }
}

// ---------------- gather aggregation + fused epilogue ----------------
// out[i] = maybe_relu( dinv[i] * ( hs[i] + sum_{e in row i} hs[csr[e]] ) + b )
// C=128: one wave per node (64 lanes x float2). C=64: half-wave per node.
template <int C, bool RELU>
__global__ __launch_bounds__(256) void agg_kernel(
    const int* __restrict__ csr, const unsigned* __restrict__ row,
    const float* __restrict__ hs, const float* __restrict__ dinv,
    const float* __restrict__ bias, float* __restrict__ out, int N) {
    constexpr int LPN = C / 2;  // lanes per node
    const int tid = blockIdx.x * 256 + threadIdx.x;
    const int i = tid / LPN;
    const int l = tid % LPN;
    if (i >= N) return;

    const size_t coff = 2 * (size_t)l;
    // self-loop term
    float2 sum = *(const float2*)(hs + (size_t)i * C + coff);

    const int rs = (int)row[i], re = (int)row[i + 1];
    for (int e0 = rs; e0 < re; e0 += LPN) {
        int idx = (e0 + l < re) ? csr[e0 + l] : 0;
        const int cnt = min(LPN, re - e0);
#pragma unroll 4
        for (int j = 0; j < cnt; j++) {
            int s = __shfl(idx, j, LPN);
            float2 v = *(const float2*)(hs + (size_t)s * C + coff);
            sum.x += v.x;
            sum.y += v.y;
        }
    }

    const float sc = dinv[i];
    const float2 b = *(const float2*)(bias + coff);
    float2 o;
    o.x = sum.x * sc + b.x;
    o.y = sum.y * sc + b.y;
    if (RELU) { o.x = fmaxf(o.x, 0.f); o.y = fmaxf(o.y, 0.f); }
    *(float2*)(out + (size_t)i * C + coff) = o;
}

// ---------------- launch ----------------
extern "C" void kernel_launch(void* const* d_in, const int* in_sizes, int n_in,
                              void* d_out, int out_size, void* d_ws,
                              size_t ws_size, hipStream_t stream) {
    const float* x  = (const float*)d_in[0];
    const float* W1 = (const float*)d_in[1];
    const float* b1 = (const float*)d_in[2];
    const float* W2 = (const float*)d_in[3];
    const float* b2 = (const float*)d_in[4];
    const unsigned* ew = (const unsigned*)d_in[5];
    const int E = in_sizes[5] / 2;      // 1,600,000
    const int N = in_sizes[0] / 128;    // 100,000
    const int NB = (N + 1023) >> 10;    // scan blocks

    char* ws = (char*)d_ws;
    unsigned* flag   = (unsigned*)(ws + OFF_FLAG);
    unsigned* deg    = (unsigned*)(ws + OFF_DEG);
    unsigned* row    = (unsigned*)(ws + OFF_ROW);
    unsigned* cursor = (unsigned*)(ws + OFF_CUR);
    unsigned* bsum   = (unsigned*)(ws + OFF_BSUM);
    float* dinv      = (float*)(ws + OFF_DINV);
    int* csr         = (int*)(ws + OFF_CSR);
    float* bufA      = (float*)(ws + OFF_BUFA);
    float* bufB      = (float*)(ws + OFF_BUFB);

    hipMemsetAsync(flag, 0, 4, stream);
    hipMemsetAsync(deg, 0, (size_t)N * 4, stream);

    // ---- CSR build ----
    detect_kernel<<<16, 256, 0, stream>>>(ew, flag);
    deg_kernel<<<(E + 255) / 256, 256, 0, stream>>>(ew, flag, deg, E);
    scan1_kernel<<<NB, 1024, 0, stream>>>(deg, row, bsum, N);
    scan2_kernel<<<1, 64, 0, stream>>>(bsum, NB);
    scan3_kernel<<<(N + 255) / 256, 256, 0, stream>>>(row, bsum, cursor, deg,
                                                      dinv, N);
    bucket_kernel<<<(E + 255) / 256, 256, 0, stream>>>(ew, flag, cursor, csr, E);

    // ---- layer 1 (C=128) ----
    gemm_scale<128><<<(N + 127) / 128, 256, 0, stream>>>(x, W1, dinv, bufA, N);
    agg_kernel<128, true><<<(N * 64 + 255) / 256, 256, 0, stream>>>(
        csr, row, bufA, dinv, b1, bufB, N);

    // ---- layer 2 (C=64) ----
    gemm_scale<64><<<(N + 127) / 128, 256, 0, stream>>>(bufB, W2, dinv, bufA, N);
    agg_kernel<64, false><<<(N * 32 + 255) / 256, 256, 0, stream>>>(
        csr, row, bufA, dinv, b2, (float*)d_out, N);
}

// Round 3
// 455.010 us; speedup vs baseline: 4.9972x; 1.3238x over previous
//
#include <hip/hip_runtime.h>

// ---------------- problem constants ----------------
// x:[N,128] W1:[128,128] b1:[128] W2:[128,64] b2:[64] edge_index:[2,E]
// out:[N,64] fp32

static constexpr int BSHIFT = 7;          // 128 node ids per coarse bucket
static constexpr int BWIDTH = 1 << BSHIFT;
static constexpr int MAXBUCK = 2048;      // supports N <= 262144

// ---------------- workspace layout (bytes) ----------------
static constexpr size_t OFF_FLAG = 0;         // u32[1]
static constexpr size_t OFF_DEG  = 256;       // u32[N]           (400 KB)
static constexpr size_t OFF_ROW  = 458752;    // u32[N+1]
static constexpr size_t OFF_BSUM = 917504;    // u32[1024]
static constexpr size_t OFF_CCNT = 925696;    // u32[MAXBUCK+1]
static constexpr size_t OFF_COFF = 937984;    // u32[MAXBUCK+1]
static constexpr size_t OFF_CCUR = 950272;    // u32[MAXBUCK]
static constexpr size_t OFF_DINV = 962560;    // f32[N]
static constexpr size_t OFF_CSR  = 1376256;   // i32[E]           (6.4 MB)
static constexpr size_t OFF_BUFA = 8388608;   // f32[N*128]       (51.2 MB)
static constexpr size_t OFF_BUFB = 59768832;  // f32[N*128]; also int2 part[E]

// ---------------- edge dtype detection ----------------
// int64 layout: high word of first 2048 elements all zero. int32: random ids.
__global__ void detect_kernel(const unsigned* __restrict__ w,
                              unsigned* __restrict__ flag) {
    int i = blockIdx.x * blockDim.x + threadIdx.x;   // 4096 threads
    if (w[2 * i + 1] != 0u) atomicOr(flag, 1u);
}

__device__ __forceinline__ int edge_dst(const unsigned* w, unsigned flag,
                                        int e, int E) {
    return flag ? (int)w[E + e] : (int)w[2 * E + 2 * e];
}
__device__ __forceinline__ int edge_src(const unsigned* w, unsigned flag,
                                        int e, int E) {
    return flag ? (int)w[e] : (int)w[2 * e];
}

// ---------------- pass A: coarse histogram (LDS hist per block) ------------
__global__ __launch_bounds__(1024) void coarse_hist_kernel(
    const unsigned* __restrict__ w, const unsigned* __restrict__ flag,
    unsigned* __restrict__ ccnt, int E, int nbuck) {
    __shared__ unsigned hist[MAXBUCK];
    for (int i = threadIdx.x; i < nbuck; i += 1024) hist[i] = 0;
    __syncthreads();
    const unsigned f = *flag;
    const int per = (E + gridDim.x - 1) / gridDim.x;
    const int e0 = blockIdx.x * per, e1 = min(E, e0 + per);
    for (int e = e0 + (int)threadIdx.x; e < e1; e += 1024)
        atomicAdd(&hist[edge_dst(w, f, e, E) >> BSHIFT], 1u);
    __syncthreads();
    for (int i = threadIdx.x; i < nbuck; i += 1024)
        if (hist[i]) atomicAdd(&ccnt[i], hist[i]);
}

// ---------------- coarse scan: coff = exclusive_scan(ccnt), init ccur ------
__global__ __launch_bounds__(1024) void coarse_scan_kernel(
    const unsigned* __restrict__ ccnt, unsigned* __restrict__ coff,
    unsigned* __restrict__ ccur, int nbuck) {
    __shared__ unsigned sh[1024];
    const int t = threadIdx.x;
    unsigned run = 0;
    for (int b0 = 0; b0 < nbuck; b0 += 1024) {
        unsigned v = (b0 + t < nbuck) ? ccnt[b0 + t] : 0u;
        sh[t] = v;
        __syncthreads();
        for (int off = 1; off < 1024; off <<= 1) {
            unsigned a = (t >= off) ? sh[t - off] : 0u;
            __syncthreads();
            sh[t] += a;
            __syncthreads();
        }
        if (b0 + t < nbuck) {
            unsigned ex = run + sh[t] - v;   // exclusive
            coff[b0 + t] = ex;
            ccur[b0 + t] = ex;
        }
        run += sh[1023];
        __syncthreads();
    }
    if (t == 0) coff[nbuck] = run;   // == E
}

// ---------------- pass B: partition edges into coarse buckets --------------
// Per block: LDS histogram -> one global range reservation per bucket ->
// append (s,d) pairs via LDS cursors. Writes are bucket-local appends.
__global__ __launch_bounds__(1024) void partition_kernel(
    const unsigned* __restrict__ w, const unsigned* __restrict__ flag,
    unsigned* __restrict__ ccur, int2* __restrict__ part, int E, int nbuck) {
    __shared__ unsigned hist[MAXBUCK];
    __shared__ unsigned lcur[MAXBUCK];
    for (int i = threadIdx.x; i < nbuck; i += 1024) hist[i] = 0;
    __syncthreads();
    const unsigned f = *flag;
    const int per = (E + gridDim.x - 1) / gridDim.x;
    const int e0 = blockIdx.x * per, e1 = min(E, e0 + per);
    for (int e = e0 + (int)threadIdx.x; e < e1; e += 1024)
        atomicAdd(&hist[edge_dst(w, f, e, E) >> BSHIFT], 1u);
    __syncthreads();
    for (int i = threadIdx.x; i < nbuck; i += 1024) {
        unsigned h = hist[i];
        lcur[i] = h ? atomicAdd(&ccur[i], h) : 0u;
    }
    __syncthreads();
    for (int e = e0 + (int)threadIdx.x; e < e1; e += 1024) {
        int d = edge_dst(w, f, e, E);
        int s = edge_src(w, f, e, E);
        unsigned pos = atomicAdd(&lcur[d >> BSHIFT], 1u);
        part[pos] = make_int2(s, d);
    }
}

// ---------------- per-bucket degree (exclusive node ownership) -------------
__global__ __launch_bounds__(256) void bucket_deg_kernel(
    const int2* __restrict__ part, const unsigned* __restrict__ coff,
    unsigned* __restrict__ deg, int N) {
    __shared__ unsigned cnt[BWIDTH];
    const int b = blockIdx.x, base = b << BSHIFT, t = threadIdx.x;
    if (t < BWIDTH) cnt[t] = 0;
    __syncthreads();
    const int e1 = (int)coff[b + 1];
    for (int e = (int)coff[b] + t; e < e1; e += 256)
        atomicAdd(&cnt[part[e].y - base], 1u);
    __syncthreads();
    if (t < BWIDTH && base + t < N) deg[base + t] = cnt[t];
}

// ---------------- scan over deg: row = exclusive_scan(deg) ----------------
__global__ __launch_bounds__(1024) void scan1_kernel(
    const unsigned* __restrict__ deg, unsigned* __restrict__ row,
    unsigned* __restrict__ bsum, int N) {
    __shared__ unsigned sh[1024];
    int gid = blockIdx.x * 1024 + threadIdx.x;
    int t = threadIdx.x;
    unsigned v = (gid < N) ? deg[gid] : 0u;
    sh[t] = v;
    __syncthreads();
#pragma unroll
    for (int off = 1; off < 1024; off <<= 1) {
        unsigned add = (t >= off) ? sh[t - off] : 0u;
        __syncthreads();
        sh[t] += add;
        __syncthreads();
    }
    if (gid < N) row[gid + 1] = sh[t];
    if (t == 1023) bsum[blockIdx.x] = sh[1023];
}

// scan2: exclusive scan of bsum (NB <= 1024), single-block parallel
__global__ __launch_bounds__(1024) void scan2_kernel(unsigned* __restrict__ bsum,
                                                     int NB) {
    __shared__ unsigned sh[1024];
    const int t = threadIdx.x;
    unsigned v = (t < NB) ? bsum[t] : 0u;
    sh[t] = v;
    __syncthreads();
#pragma unroll
    for (int off = 1; off < 1024; off <<= 1) {
        unsigned a = (t >= off) ? sh[t - off] : 0u;
        __syncthreads();
        sh[t] += a;
        __syncthreads();
    }
    if (t < NB) bsum[t] = sh[t] - v;   // exclusive
}

// scan3: finalize row, compute dinv
__global__ void scan3_kernel(unsigned* __restrict__ row,
                             const unsigned* __restrict__ bsum,
                             const unsigned* __restrict__ deg,
                             float* __restrict__ dinv, int N) {
    int gid = blockIdx.x * blockDim.x + threadIdx.x;
    if (gid >= N) return;
    row[gid + 1] += bsum[gid >> 10];
    if (gid == 0) row[0] = 0u;
    dinv[gid] = rsqrtf((float)deg[gid] + 1.0f);
}

// ---------------- pass D: final CSR bucket (bucket-local writes) -----------
__global__ __launch_bounds__(256) void fine_bucket_kernel(
    const int2* __restrict__ part, const unsigned* __restrict__ coff,
    const unsigned* __restrict__ row, int* __restrict__ csr, int N) {
    __shared__ unsigned cur[BWIDTH];
    const int b = blockIdx.x, base = b << BSHIFT, t = threadIdx.x;
    if (t < BWIDTH && base + t < N) cur[t] = row[base + t];
    __syncthreads();
    const int e1 = (int)coff[b + 1];
    for (int e = (int)coff[b] + t; e < e1; e += 256) {
        int2 sd = part[e];
        unsigned pos = atomicAdd(&cur[sd.y - base], 1u);
        csr[pos] = sd.x;
    }
}

// ---------------- fp32 GEMM, out = (A @ B) * dinv[row] ----------------
template <int BN>
__global__ __launch_bounds__(256) void gemm_scale(
    const float* __restrict__ A, const float* __restrict__ B,
    const float* __restrict__ dinv, float* __restrict__ out, int M) {
    constexpr int K = 128, BM = 128, KT = 32;
    constexpr int LDA = KT + 4;
    constexpr int LDB = BN + 4;
    constexpr int NCH = BN / 64;
    __shared__ float sA[BM * LDA];
    __shared__ float sB[KT * LDB];

    const int t = threadIdx.x;
    const int row0 = blockIdx.x * BM;
    const int tx = t & 15, ty = t >> 4;

    float4 acc[8][NCH];
#pragma unroll
    for (int i = 0; i < 8; i++)
#pragma unroll
        for (int ch = 0; ch < NCH; ch++) acc[i][ch] = make_float4(0.f, 0.f, 0.f, 0.f);

    for (int kt = 0; kt < K; kt += KT) {
        for (int idx = t * 4; idx < BM * KT; idx += 1024) {
            int r = idx / KT, k = idx - r * KT;
            float4 v = make_float4(0.f, 0.f, 0.f, 0.f);
            int row = row0 + r;
            if (row < M) v = *(const float4*)(A + (size_t)row * K + kt + k);
            float* p = sA + r * LDA + k;
            p[0] = v.x; p[1] = v.y; p[2] = v.z; p[3] = v.w;
        }
        for (int idx = t * 4; idx < KT * BN; idx += 1024) {
            int k = idx / BN, c = idx - k * BN;
            float4 v = *(const float4*)(B + (size_t)(kt + k) * BN + c);
            float* p = sB + k * LDB + c;
            p[0] = v.x; p[1] = v.y; p[2] = v.z; p[3] = v.w;
        }
        __syncthreads();

        for (int k = 0; k < KT; k += 4) {
            float4 a[8];
#pragma unroll
            for (int i = 0; i < 8; i++)
                a[i] = *(const float4*)(sA + (ty + 16 * i) * LDA + k);
#pragma unroll
            for (int kk = 0; kk < 4; kk++) {
                float4 b[NCH];
#pragma unroll
                for (int ch = 0; ch < NCH; ch++)
                    b[ch] = *(const float4*)(sB + (k + kk) * LDB + ch * 64 + tx * 4);
#pragma unroll
                for (int i = 0; i < 8; i++) {
                    float av = (kk == 0) ? a[i].x : (kk == 1) ? a[i].y
                             : (kk == 2) ? a[i].z : a[i].w;
#pragma unroll
                    for (int ch = 0; ch < NCH; ch++) {
                        acc[i][ch].x += av * b[ch].x;
                        acc[i][ch].y += av * b[ch].y;
                        acc[i][ch].z += av * b[ch].z;
                        acc[i][ch].w += av * b[ch].w;
                    }
                }
            }
        }
        __syncthreads();
    }

#pragma unroll
    for (int i = 0; i < 8; i++) {
        int row = row0 + ty + 16 * i;
        if (row < M) {
            float s = dinv[row];
#pragma unroll
            for (int ch = 0; ch < NCH; ch++) {
                float4 v = acc[i][ch];
                v.x *= s; v.y *= s; v.z *= s; v.w *= s;
                *(float4*)(out + (size_t)row * BN + ch * 64 + tx * 4) = v;
            }
        }
    }
}

// ---------------- gather aggregation + fused epilogue ----------------
// out[i] = maybe_relu( dinv[i] * ( hs[i] + sum_{e in row i} hs[csr[e]] ) + b )
template <int C, bool RELU>
__global__ __launch_bounds__(256) void agg_kernel(
    const int* __restrict__ csr, const unsigned* __restrict__ row,
    const float* __restrict__ hs, const float* __restrict__ dinv,
    const float* __restrict__ bias, float* __restrict__ out, int N) {
    constexpr int LPN = C / 2;  // lanes per node
    const int tid = blockIdx.x * 256 + threadIdx.x;
    const int i = tid / LPN;
    const int l = tid % LPN;
    if (i >= N) return;

    const size_t coff = 2 * (size_t)l;
    float2 sum = *(const float2*)(hs + (size_t)i * C + coff);  // self-loop

    const int rs = (int)row[i], re = (int)row[i + 1];
    for (int e0 = rs; e0 < re; e0 += LPN) {
        int idx = (e0 + l < re) ? csr[e0 + l] : 0;
        const int cnt = min(LPN, re - e0);
#pragma unroll 4
        for (int j = 0; j < cnt; j++) {
            int s = __shfl(idx, j, LPN);
            float2 v = *(const float2*)(hs + (size_t)s * C + coff);
            sum.x += v.x;
            sum.y += v.y;
        }
    }

    const float sc = dinv[i];
    const float2 b = *(const float2*)(bias + coff);
    float2 o;
    o.x = sum.x * sc + b.x;
    o.y = sum.y * sc + b.y;
    if (RELU) { o.x = fmaxf(o.x, 0.f); o.y = fmaxf(o.y, 0.f); }
    *(float2*)(out + (size_t)i * C + coff) = o;
}

// ---------------- launch ----------------
extern "C" void kernel_launch(void* const* d_in, const int* in_sizes, int n_in,
                              void* d_out, int out_size, void* d_ws,
                              size_t ws_size, hipStream_t stream) {
    const float* x  = (const float*)d_in[0];
    const float* W1 = (const float*)d_in[1];
    const float* b1 = (const float*)d_in[2];
    const float* W2 = (const float*)d_in[3];
    const float* b2 = (const float*)d_in[4];
    const unsigned* ew = (const unsigned*)d_in[5];
    const int E = in_sizes[5] / 2;        // 1,600,000
    const int N = in_sizes[0] / 128;      // 100,000
    const int NB = (N + 1023) >> 10;      // scan1 blocks
    const int nbuck = (N + BWIDTH - 1) >> BSHIFT;   // 782

    char* ws = (char*)d_ws;
    unsigned* flag = (unsigned*)(ws + OFF_FLAG);
    unsigned* deg  = (unsigned*)(ws + OFF_DEG);
    unsigned* row  = (unsigned*)(ws + OFF_ROW);
    unsigned* bsum = (unsigned*)(ws + OFF_BSUM);
    unsigned* ccnt = (unsigned*)(ws + OFF_CCNT);
    unsigned* coff = (unsigned*)(ws + OFF_COFF);
    unsigned* ccur = (unsigned*)(ws + OFF_CCUR);
    float* dinv    = (float*)(ws + OFF_DINV);
    int* csr       = (int*)(ws + OFF_CSR);
    float* bufA    = (float*)(ws + OFF_BUFA);
    float* bufB    = (float*)(ws + OFF_BUFB);
    int2* part     = (int2*)(ws + OFF_BUFB);   // dead before agg1 writes bufB

    hipMemsetAsync(flag, 0, 4, stream);
    hipMemsetAsync(ccnt, 0, (size_t)(nbuck + 1) * 4, stream);

    // ---- CSR build (two-level bucketing, no global-random stores) ----
    detect_kernel<<<16, 256, 0, stream>>>(ew, flag);
    coarse_hist_kernel<<<256, 1024, 0, stream>>>(ew, flag, ccnt, E, nbuck);
    coarse_scan_kernel<<<1, 1024, 0, stream>>>(ccnt, coff, ccur, nbuck);
    partition_kernel<<<256, 1024, 0, stream>>>(ew, flag, ccur, part, E, nbuck);
    bucket_deg_kernel<<<nbuck, 256, 0, stream>>>(part, coff, deg, N);
    scan1_kernel<<<NB, 1024, 0, stream>>>(deg, row, bsum, N);
    scan2_kernel<<<1, 1024, 0, stream>>>(bsum, NB);
    scan3_kernel<<<(N + 255) / 256, 256, 0, stream>>>(row, bsum, deg, dinv, N);
    fine_bucket_kernel<<<nbuck, 256, 0, stream>>>(part, coff, row, csr, N);

    // ---- layer 1 (C=128) ----
    gemm_scale<128><<<(N + 127) / 128, 256, 0, stream>>>(x, W1, dinv, bufA, N);
    agg_kernel<128, true><<<(N * 64 + 255) / 256, 256, 0, stream>>>(
        csr, row, bufA, dinv, b1, bufB, N);

    // ---- layer 2 (C=64) ----
    gemm_scale<64><<<(N + 127) / 128, 256, 0, stream>>>(bufB, W2, dinv, bufA, N);
    agg_kernel<64, false><<<(N * 32 + 255) / 256, 256, 0, stream>>>(
        csr, row, bufA, dinv, b2, (float*)d_out, N);
}

// Round 4
// 352.533 us; speedup vs baseline: 6.4499x; 1.2907x over previous
//
#include <hip/hip_runtime.h>

// ---------------- problem constants ----------------
// x:[N,128] W1:[128,128] b1:[128] W2:[128,64] b2:[64] edge_index:[2,E]
// out:[N,64] fp32. Intermediates stored bf16 (threshold is bf16-grade 4.2e-3).

static constexpr int BSHIFT = 7;          // 128 node ids per coarse bucket
static constexpr int BWIDTH = 1 << BSHIFT;
static constexpr int MAXBUCK = 2048;      // supports N <= 262144 (pack needs N < 2^20)

// ---------------- workspace layout (bytes) ----------------
static constexpr size_t OFF_FLAG = 0;         // u32[1]
static constexpr size_t OFF_DEG  = 256;       // u32[N]
static constexpr size_t OFF_ROW  = 458752;    // u32[N+1]
static constexpr size_t OFF_BSUM = 917504;    // u32[1024]
static constexpr size_t OFF_CCNT = 925696;    // u32[MAXBUCK+1]
static constexpr size_t OFF_COFF = 937984;    // u32[MAXBUCK+1]
static constexpr size_t OFF_CCUR = 950272;    // u32[MAXBUCK]
static constexpr size_t OFF_DINV = 962560;    // f32[N]
static constexpr size_t OFF_CSR  = 1376256;   // i32[E]            (6.4 MB)
static constexpr size_t OFF_HS1  = 8388608;   // bf16[N*128] 25.6 MB; aliases part u32[E]
static constexpr size_t OFF_OUT1 = 35651584;  // bf16[N*128] 25.6 MB
static constexpr size_t OFF_HS2  = 62914560;  // bf16[N*64]  12.8 MB

// ---------------- bf16 helpers ----------------
__device__ __forceinline__ float bf2f(unsigned short u) {
    return __uint_as_float((unsigned)u << 16);
}
__device__ __forceinline__ unsigned short f2bf(float f) {  // RNE
    unsigned u = __float_as_uint(f);
    u += 0x7fffu + ((u >> 16) & 1u);
    return (unsigned short)(u >> 16);
}
__device__ __forceinline__ float4 bf4_to_f4(ushort4 v) {
    float4 r;
    r.x = bf2f(v.x); r.y = bf2f(v.y); r.z = bf2f(v.z); r.w = bf2f(v.w);
    return r;
}

// ---------------- edge dtype detection ----------------
__global__ void detect_kernel(const unsigned* __restrict__ w,
                              unsigned* __restrict__ flag) {
    int i = blockIdx.x * blockDim.x + threadIdx.x;   // 4096 threads
    if (w[2 * i + 1] != 0u) atomicOr(flag, 1u);
}

__device__ __forceinline__ int edge_dst(const unsigned* w, unsigned flag,
                                        int e, int E) {
    return flag ? (int)w[E + e] : (int)w[2 * E + 2 * e];
}
__device__ __forceinline__ int edge_src(const unsigned* w, unsigned flag,
                                        int e, int E) {
    return flag ? (int)w[e] : (int)w[2 * e];
}

// ---------------- pass A: coarse histogram ----------------
__global__ __launch_bounds__(1024) void coarse_hist_kernel(
    const unsigned* __restrict__ w, const unsigned* __restrict__ flag,
    unsigned* __restrict__ ccnt, int E, int nbuck) {
    __shared__ unsigned hist[MAXBUCK];
    for (int i = threadIdx.x; i < nbuck; i += 1024) hist[i] = 0;
    __syncthreads();
    const unsigned f = *flag;
    const int per = (E + gridDim.x - 1) / gridDim.x;
    const int e0 = blockIdx.x * per, e1 = min(E, e0 + per);
    for (int e = e0 + (int)threadIdx.x; e < e1; e += 1024)
        atomicAdd(&hist[edge_dst(w, f, e, E) >> BSHIFT], 1u);
    __syncthreads();
    for (int i = threadIdx.x; i < nbuck; i += 1024)
        if (hist[i]) atomicAdd(&ccnt[i], hist[i]);
}

// ---------------- coarse scan ----------------
__global__ __launch_bounds__(1024) void coarse_scan_kernel(
    const unsigned* __restrict__ ccnt, unsigned* __restrict__ coff,
    unsigned* __restrict__ ccur, int nbuck) {
    __shared__ unsigned sh[1024];
    const int t = threadIdx.x;
    unsigned run = 0;
    for (int b0 = 0; b0 < nbuck; b0 += 1024) {
        unsigned v = (b0 + t < nbuck) ? ccnt[b0 + t] : 0u;
        sh[t] = v;
        __syncthreads();
        for (int off = 1; off < 1024; off <<= 1) {
            unsigned a = (t >= off) ? sh[t - off] : 0u;
            __syncthreads();
            sh[t] += a;
            __syncthreads();
        }
        if (b0 + t < nbuck) {
            unsigned ex = run + sh[t] - v;
            coff[b0 + t] = ex;
            ccur[b0 + t] = ex;
        }
        run += sh[1023];
        __syncthreads();
    }
    if (t == 0) coff[nbuck] = run;   // == E
}

// ---------------- pass B: partition (packed 4 B entries) ----------------
// part entry = src | (dst&127)<<20  (valid: N < 2^20)
__global__ __launch_bounds__(1024) void partition_kernel(
    const unsigned* __restrict__ w, const unsigned* __restrict__ flag,
    unsigned* __restrict__ ccur, unsigned* __restrict__ part, int E, int nbuck) {
    __shared__ unsigned hist[MAXBUCK];
    __shared__ unsigned lcur[MAXBUCK];
    for (int i = threadIdx.x; i < nbuck; i += 1024) hist[i] = 0;
    __syncthreads();
    const unsigned f = *flag;
    const int per = (E + gridDim.x - 1) / gridDim.x;
    const int e0 = blockIdx.x * per, e1 = min(E, e0 + per);
    for (int e = e0 + (int)threadIdx.x; e < e1; e += 1024)
        atomicAdd(&hist[edge_dst(w, f, e, E) >> BSHIFT], 1u);
    __syncthreads();
    for (int i = threadIdx.x; i < nbuck; i += 1024) {
        unsigned h = hist[i];
        lcur[i] = h ? atomicAdd(&ccur[i], h) : 0u;
    }
    __syncthreads();
    for (int e = e0 + (int)threadIdx.x; e < e1; e += 1024) {
        int d = edge_dst(w, f, e, E);
        int s = edge_src(w, f, e, E);
        unsigned pos = atomicAdd(&lcur[d >> BSHIFT], 1u);
        part[pos] = (unsigned)s | ((unsigned)(d & (BWIDTH - 1)) << 20);
    }
}

// ---------------- pass C: per-bucket deg + local scan + CSR write ----------
// Valid because coff[b] == row[b<<BSHIFT] (bucket order == node order).
__global__ __launch_bounds__(256) void bucket_csr_kernel(
    const unsigned* __restrict__ part, const unsigned* __restrict__ coff,
    unsigned* __restrict__ deg, int* __restrict__ csr, int N) {
    __shared__ unsigned cnt[BWIDTH];
    __shared__ unsigned sc[BWIDTH];
    __shared__ unsigned cur[BWIDTH];
    const int b = blockIdx.x, base = b << BSHIFT, t = threadIdx.x;
    if (t < BWIDTH) cnt[t] = 0;
    __syncthreads();
    const int e0 = (int)coff[b], e1 = (int)coff[b + 1];
    for (int e = e0 + t; e < e1; e += 256)
        atomicAdd(&cnt[part[e] >> 20], 1u);
    __syncthreads();
    if (t < BWIDTH && base + t < N) deg[base + t] = cnt[t];
    if (t < BWIDTH) sc[t] = cnt[t];
    __syncthreads();
#pragma unroll
    for (int off = 1; off < BWIDTH; off <<= 1) {
        unsigned a = (t < BWIDTH && t >= off) ? sc[t - off] : 0u;
        __syncthreads();
        if (t < BWIDTH) sc[t] += a;
        __syncthreads();
    }
    if (t < BWIDTH) cur[t] = (unsigned)e0 + sc[t] - cnt[t];
    __syncthreads();
    for (int e = e0 + t; e < e1; e += 256) {
        unsigned pk = part[e];
        unsigned p = atomicAdd(&cur[pk >> 20], 1u);
        csr[p] = (int)(pk & 0xFFFFFu);
    }
}

// ---------------- scans over deg -> row; dinv ----------------
__global__ __launch_bounds__(1024) void scan1_kernel(
    const unsigned* __restrict__ deg, unsigned* __restrict__ row,
    unsigned* __restrict__ bsum, int N) {
    __shared__ unsigned sh[1024];
    int gid = blockIdx.x * 1024 + threadIdx.x;
    int t = threadIdx.x;
    unsigned v = (gid < N) ? deg[gid] : 0u;
    sh[t] = v;
    __syncthreads();
#pragma unroll
    for (int off = 1; off < 1024; off <<= 1) {
        unsigned add = (t >= off) ? sh[t - off] : 0u;
        __syncthreads();
        sh[t] += add;
        __syncthreads();
    }
    if (gid < N) row[gid + 1] = sh[t];
    if (t == 1023) bsum[blockIdx.x] = sh[1023];
}

__global__ __launch_bounds__(1024) void scan2_kernel(unsigned* __restrict__ bsum,
                                                     int NB) {
    __shared__ unsigned sh[1024];
    const int t = threadIdx.x;
    unsigned v = (t < NB) ? bsum[t] : 0u;
    sh[t] = v;
    __syncthreads();
#pragma unroll
    for (int off = 1; off < 1024; off <<= 1) {
        unsigned a = (t >= off) ? sh[t - off] : 0u;
        __syncthreads();
        sh[t] += a;
        __syncthreads();
    }
    if (t < NB) bsum[t] = sh[t] - v;
}

__global__ void scan3_kernel(unsigned* __restrict__ row,
                             const unsigned* __restrict__ bsum,
                             const unsigned* __restrict__ deg,
                             float* __restrict__ dinv, int N) {
    int gid = blockIdx.x * blockDim.x + threadIdx.x;
    if (gid >= N) return;
    row[gid + 1] += bsum[gid >> 10];
    if (gid == 0) row[0] = 0u;
    dinv[gid] = rsqrtf((float)deg[gid] + 1.0f);
}

// ---------------- GEMM: out_bf16 = (A @ B) * dinv[row] ----------------
// A fp32 or bf16 (converted to fp32 during LDS staging); math fp32.
template <int BN, bool ABF16>
__global__ __launch_bounds__(256) void gemm_scale(
    const void* __restrict__ Av, const float* __restrict__ B,
    const float* __restrict__ dinv, unsigned short* __restrict__ out, int M) {
    constexpr int K = 128, BM = 128, KT = 32;
    constexpr int LDA = KT + 4;
    constexpr int LDB = BN + 4;
    constexpr int NCH = BN / 64;
    __shared__ float sA[BM * LDA];
    __shared__ float sB[KT * LDB];

    const int t = threadIdx.x;
    const int row0 = blockIdx.x * BM;
    const int tx = t & 15, ty = t >> 4;

    float4 acc[8][NCH];
#pragma unroll
    for (int i = 0; i < 8; i++)
#pragma unroll
        for (int ch = 0; ch < NCH; ch++) acc[i][ch] = make_float4(0.f, 0.f, 0.f, 0.f);

    for (int kt = 0; kt < K; kt += KT) {
        for (int idx = t * 4; idx < BM * KT; idx += 1024) {
            int r = idx / KT, k = idx - r * KT;
            float4 v = make_float4(0.f, 0.f, 0.f, 0.f);
            int row = row0 + r;
            if (row < M) {
                if (ABF16) {
                    ushort4 u = *(const ushort4*)((const unsigned short*)Av +
                                                  (size_t)row * K + kt + k);
                    v = bf4_to_f4(u);
                } else {
                    v = *(const float4*)((const float*)Av + (size_t)row * K + kt + k);
                }
            }
            float* p = sA + r * LDA + k;
            p[0] = v.x; p[1] = v.y; p[2] = v.z; p[3] = v.w;
        }
        for (int idx = t * 4; idx < KT * BN; idx += 1024) {
            int k = idx / BN, c = idx - k * BN;
            float4 v = *(const float4*)(B + (size_t)(kt + k) * BN + c);
            float* p = sB + k * LDB + c;
            p[0] = v.x; p[1] = v.y; p[2] = v.z; p[3] = v.w;
        }
        __syncthreads();

        for (int k = 0; k < KT; k += 4) {
            float4 a[8];
#pragma unroll
            for (int i = 0; i < 8; i++)
                a[i] = *(const float4*)(sA + (ty + 16 * i) * LDA + k);
#pragma unroll
            for (int kk = 0; kk < 4; kk++) {
                float4 b[NCH];
#pragma unroll
                for (int ch = 0; ch < NCH; ch++)
                    b[ch] = *(const float4*)(sB + (k + kk) * LDB + ch * 64 + tx * 4);
#pragma unroll
                for (int i = 0; i < 8; i++) {
                    float av = (kk == 0) ? a[i].x : (kk == 1) ? a[i].y
                             : (kk == 2) ? a[i].z : a[i].w;
#pragma unroll
                    for (int ch = 0; ch < NCH; ch++) {
                        acc[i][ch].x += av * b[ch].x;
                        acc[i][ch].y += av * b[ch].y;
                        acc[i][ch].z += av * b[ch].z;
                        acc[i][ch].w += av * b[ch].w;
                    }
                }
            }
        }
        __syncthreads();
    }

#pragma unroll
    for (int i = 0; i < 8; i++) {
        int row = row0 + ty + 16 * i;
        if (row < M) {
            float s = dinv[row];
#pragma unroll
            for (int ch = 0; ch < NCH; ch++) {
                float4 v = acc[i][ch];
                ushort4 o;
                o.x = f2bf(v.x * s); o.y = f2bf(v.y * s);
                o.z = f2bf(v.z * s); o.w = f2bf(v.w * s);
                *(ushort4*)(out + (size_t)row * BN + ch * 64 + tx * 4) = o;
            }
        }
    }
}

// ---------------- gather aggregation + fused epilogue (bf16 table) ---------
// out[i] = maybe_relu( dinv[i] * ( hs[i] + sum_{e in row i} hs[csr[e]] ) + b )
// Lane owns 4 channels (ushort4 = 8 B). LPN = C/4 lanes per node.
template <int C, bool RELU, bool OUTBF>
__global__ __launch_bounds__(256) void agg_kernel(
    const int* __restrict__ csr, const unsigned* __restrict__ row,
    const unsigned short* __restrict__ hsb, const float* __restrict__ dinv,
    const float* __restrict__ bias, void* __restrict__ outv, int N) {
    constexpr int LPN = C / 4;  // lanes per node (32 or 16)
    const int tid = blockIdx.x * 256 + threadIdx.x;
    const int i = tid / LPN;
    const int l = tid % LPN;
    if (i >= N) return;

    const int co = 4 * l;
    float4 sum = bf4_to_f4(*(const ushort4*)(hsb + (size_t)i * C + co));  // self

    const int rs = (int)row[i], re = (int)row[i + 1];
    for (int e0 = rs; e0 < re; e0 += LPN) {
        int idx = (e0 + l < re) ? csr[e0 + l] : 0;
        const int cnt = min(LPN, re - e0);
#pragma unroll 4
        for (int j = 0; j < cnt; j++) {
            int s = __shfl(idx, j, LPN);
            float4 v = bf4_to_f4(*(const ushort4*)(hsb + (size_t)s * C + co));
            sum.x += v.x; sum.y += v.y; sum.z += v.z; sum.w += v.w;
        }
    }

    const float sc = dinv[i];
    const float4 b = *(const float4*)(bias + co);
    float4 o;
    o.x = sum.x * sc + b.x;
    o.y = sum.y * sc + b.y;
    o.z = sum.z * sc + b.z;
    o.w = sum.w * sc + b.w;
    if (RELU) {
        o.x = fmaxf(o.x, 0.f); o.y = fmaxf(o.y, 0.f);
        o.z = fmaxf(o.z, 0.f); o.w = fmaxf(o.w, 0.f);
    }
    if (OUTBF) {
        ushort4 u;
        u.x = f2bf(o.x); u.y = f2bf(o.y); u.z = f2bf(o.z); u.w = f2bf(o.w);
        *(ushort4*)((unsigned short*)outv + (size_t)i * C + co) = u;
    } else {
        *(float4*)((float*)outv + (size_t)i * C + co) = o;
    }
}

// ---------------- launch ----------------
extern "C" void kernel_launch(void* const* d_in, const int* in_sizes, int n_in,
                              void* d_out, int out_size, void* d_ws,
                              size_t ws_size, hipStream_t stream) {
    const float* x  = (const float*)d_in[0];
    const float* W1 = (const float*)d_in[1];
    const float* b1 = (const float*)d_in[2];
    const float* W2 = (const float*)d_in[3];
    const float* b2 = (const float*)d_in[4];
    const unsigned* ew = (const unsigned*)d_in[5];
    const int E = in_sizes[5] / 2;        // 1,600,000
    const int N = in_sizes[0] / 128;      // 100,000
    const int NB = (N + 1023) >> 10;
    const int nbuck = (N + BWIDTH - 1) >> BSHIFT;   // 782

    char* ws = (char*)d_ws;
    unsigned* flag = (unsigned*)(ws + OFF_FLAG);
    unsigned* deg  = (unsigned*)(ws + OFF_DEG);
    unsigned* row  = (unsigned*)(ws + OFF_ROW);
    unsigned* bsum = (unsigned*)(ws + OFF_BSUM);
    unsigned* ccnt = (unsigned*)(ws + OFF_CCNT);
    unsigned* coff = (unsigned*)(ws + OFF_COFF);
    unsigned* ccur = (unsigned*)(ws + OFF_CCUR);
    float* dinv    = (float*)(ws + OFF_DINV);
    int* csr       = (int*)(ws + OFF_CSR);
    unsigned short* hs1  = (unsigned short*)(ws + OFF_HS1);
    unsigned short* out1 = (unsigned short*)(ws + OFF_OUT1);
    unsigned short* hs2  = (unsigned short*)(ws + OFF_HS2);
    unsigned* part = (unsigned*)(ws + OFF_HS1);  // dead before gemm1 writes hs1

    hipMemsetAsync(flag, 0, 4, stream);
    hipMemsetAsync(ccnt, 0, (size_t)(nbuck + 1) * 4, stream);

    // ---- CSR build ----
    detect_kernel<<<16, 256, 0, stream>>>(ew, flag);
    coarse_hist_kernel<<<256, 1024, 0, stream>>>(ew, flag, ccnt, E, nbuck);
    coarse_scan_kernel<<<1, 1024, 0, stream>>>(ccnt, coff, ccur, nbuck);
    partition_kernel<<<256, 1024, 0, stream>>>(ew, flag, ccur, part, E, nbuck);
    bucket_csr_kernel<<<nbuck, 256, 0, stream>>>(part, coff, deg, csr, N);
    scan1_kernel<<<NB, 1024, 0, stream>>>(deg, row, bsum, N);
    scan2_kernel<<<1, 1024, 0, stream>>>(bsum, NB);
    scan3_kernel<<<(N + 255) / 256, 256, 0, stream>>>(row, bsum, deg, dinv, N);

    // ---- layer 1 (C=128) ----
    gemm_scale<128, false><<<(N + 127) / 128, 256, 0, stream>>>(x, W1, dinv, hs1, N);
    agg_kernel<128, true, true><<<(N * 32 + 255) / 256, 256, 0, stream>>>(
        csr, row, hs1, dinv, b1, out1, N);

    // ---- layer 2 (C=64) ----
    gemm_scale<64, true><<<(N + 127) / 128, 256, 0, stream>>>(out1, W2, dinv, hs2, N);
    agg_kernel<64, false, false><<<(N * 16 + 255) / 256, 256, 0, stream>>>(
        csr, row, hs2, dinv, b2, d_out, N);
}

// Round 5
// 317.566 us; speedup vs baseline: 7.1601x; 1.1101x over previous
//
#include <hip/hip_runtime.h>

// ---------------- problem constants ----------------
// x:[N,128] W1:[128,128] b1:[128] W2:[128,64] b2:[64] edge_index:[2,E]
// out:[N,64] fp32. Intermediates bf16; GEMMs use bf16 MFMA (fp32 accum).

static constexpr int BSHIFT = 7;          // 128 node ids per coarse bucket
static constexpr int BWIDTH = 1 << BSHIFT;
static constexpr int MAXBUCK = 2048;      // supports N <= 262144 (pack needs N < 2^20)
static constexpr int NPART = 256;         // partition/hist grid size

// ---------------- workspace layout (bytes) ----------------
static constexpr size_t OFF_FLAG = 0;         // u32[1]
static constexpr size_t OFF_DEG  = 256;       // u32[N]
static constexpr size_t OFF_ROW  = 458752;    // u32[N+1]
static constexpr size_t OFF_BSUM = 917504;    // u32[1024]
static constexpr size_t OFF_CCNT = 925696;    // u32[MAXBUCK+1]
static constexpr size_t OFF_COFF = 937984;    // u32[MAXBUCK+1]
static constexpr size_t OFF_DINV = 962560;    // f32[N]
static constexpr size_t OFF_CSR  = 1376256;   // i32[E]            (6.4 MB)
static constexpr size_t OFF_HS1  = 8388608;   // bf16[N*128] 25.6 MB; aliases part u32[E]
static constexpr size_t OFF_OUT1 = 35651584;  // bf16[N*128] 25.6 MB
static constexpr size_t OFF_HS2  = 62914560;  // bf16[N*64]  12.8 MB (ends 75714560)
static constexpr size_t OFF_H2   = 75714560;  // u32[MAXBUCK*NPART] (800 KB used)

// ---------------- bf16 helpers ----------------
__device__ __forceinline__ unsigned short f2bf(float f) {  // RNE
    unsigned u = __float_as_uint(f);
    u += 0x7fffu + ((u >> 16) & 1u);
    return (unsigned short)(u >> 16);
}

typedef __attribute__((ext_vector_type(8))) short bf16x8;
typedef __attribute__((ext_vector_type(4))) float f32x4;

// ---------------- edge dtype detection ----------------
__global__ void detect_kernel(const unsigned* __restrict__ w,
                              unsigned* __restrict__ flag) {
    int i = blockIdx.x * blockDim.x + threadIdx.x;   // 4096 threads
    if (w[2 * i + 1] != 0u) atomicOr(flag, 1u);
}

__device__ __forceinline__ int edge_dst(const unsigned* w, unsigned flag,
                                        int e, int E) {
    return flag ? (int)w[E + e] : (int)w[2 * E + 2 * e];
}
__device__ __forceinline__ int edge_src(const unsigned* w, unsigned flag,
                                        int e, int E) {
    return flag ? (int)w[e] : (int)w[2 * e];
}

// ---------------- pass A: coarse histogram (stores per-block hist) ---------
__global__ __launch_bounds__(1024) void coarse_hist_kernel(
    const unsigned* __restrict__ w, const unsigned* __restrict__ flag,
    unsigned* __restrict__ ccnt, unsigned* __restrict__ h2, int E, int nbuck) {
    __shared__ unsigned hist[MAXBUCK];
    for (int i = threadIdx.x; i < nbuck; i += 1024) hist[i] = 0;
    __syncthreads();
    const unsigned f = *flag;
    const int per = (E + gridDim.x - 1) / gridDim.x;
    const int e0 = blockIdx.x * per, e1 = min(E, e0 + per);
    for (int e = e0 + (int)threadIdx.x; e < e1; e += 1024)
        atomicAdd(&hist[edge_dst(w, f, e, E) >> BSHIFT], 1u);
    __syncthreads();
    for (int i = threadIdx.x; i < nbuck; i += 1024) {
        unsigned h = hist[i];
        h2[(size_t)i * NPART + blockIdx.x] = h;
        if (h) atomicAdd(&ccnt[i], h);
    }
}

// ---------------- coarse scan: coff = exclusive_scan(ccnt) ----------------
__global__ __launch_bounds__(1024) void coarse_scan_kernel(
    const unsigned* __restrict__ ccnt, unsigned* __restrict__ coff, int nbuck) {
    __shared__ unsigned sh[1024];
    const int t = threadIdx.x;
    unsigned run = 0;
    for (int b0 = 0; b0 < nbuck; b0 += 1024) {
        unsigned v = (b0 + t < nbuck) ? ccnt[b0 + t] : 0u;
        sh[t] = v;
        __syncthreads();
        for (int off = 1; off < 1024; off <<= 1) {
            unsigned a = (t >= off) ? sh[t - off] : 0u;
            __syncthreads();
            sh[t] += a;
            __syncthreads();
        }
        if (b0 + t < nbuck) coff[b0 + t] = run + sh[t] - v;
        run += sh[1023];
        __syncthreads();
    }
    if (t == 0) coff[nbuck] = run;   // == E
}

// ---------------- off2d: h2[b][blk] -> per-block write cursor --------------
__global__ __launch_bounds__(NPART) void off2d_kernel(
    unsigned* __restrict__ h2, const unsigned* __restrict__ coff) {
    __shared__ unsigned sh[NPART];
    const int b = blockIdx.x, t = threadIdx.x;
    unsigned v = h2[(size_t)b * NPART + t];
    sh[t] = v;
    __syncthreads();
#pragma unroll
    for (int off = 1; off < NPART; off <<= 1) {
        unsigned a = (t >= off) ? sh[t - off] : 0u;
        __syncthreads();
        sh[t] += a;
        __syncthreads();
    }
    h2[(size_t)b * NPART + t] = coff[b] + sh[t] - v;   // exclusive + base
}

// ---------------- pass B: partition (packed 4 B entries) ----------------
// part entry = src | (dst&127)<<20  (valid: N < 2^20)
__global__ __launch_bounds__(1024) void partition_kernel(
    const unsigned* __restrict__ w, const unsigned* __restrict__ flag,
    const unsigned* __restrict__ h2, unsigned* __restrict__ part, int E,
    int nbuck) {
    __shared__ unsigned lcur[MAXBUCK];
    for (int i = threadIdx.x; i < nbuck; i += 1024)
        lcur[i] = h2[(size_t)i * NPART + blockIdx.x];
    __syncthreads();
    const unsigned f = *flag;
    const int per = (E + gridDim.x - 1) / gridDim.x;
    const int e0 = blockIdx.x * per, e1 = min(E, e0 + per);
    for (int e = e0 + (int)threadIdx.x; e < e1; e += 1024) {
        int d = edge_dst(w, f, e, E);
        int s = edge_src(w, f, e, E);
        unsigned pos = atomicAdd(&lcur[d >> BSHIFT], 1u);
        part[pos] = (unsigned)s | ((unsigned)(d & (BWIDTH - 1)) << 20);
    }
}

// ---------------- pass C: per-bucket deg + local scan + CSR write ----------
__global__ __launch_bounds__(256) void bucket_csr_kernel(
    const unsigned* __restrict__ part, const unsigned* __restrict__ coff,
    unsigned* __restrict__ deg, int* __restrict__ csr, int N) {
    __shared__ unsigned cnt[BWIDTH];
    __shared__ unsigned sc[BWIDTH];
    __shared__ unsigned cur[BWIDTH];
    const int b = blockIdx.x, base = b << BSHIFT, t = threadIdx.x;
    if (t < BWIDTH) cnt[t] = 0;
    __syncthreads();
    const int e0 = (int)coff[b], e1 = (int)coff[b + 1];
    for (int e = e0 + t; e < e1; e += 256)
        atomicAdd(&cnt[part[e] >> 20], 1u);
    __syncthreads();
    if (t < BWIDTH && base + t < N) deg[base + t] = cnt[t];
    if (t < BWIDTH) sc[t] = cnt[t];
    __syncthreads();
#pragma unroll
    for (int off = 1; off < BWIDTH; off <<= 1) {
        unsigned a = (t < BWIDTH && t >= off) ? sc[t - off] : 0u;
        __syncthreads();
        if (t < BWIDTH) sc[t] += a;
        __syncthreads();
    }
    if (t < BWIDTH) cur[t] = (unsigned)e0 + sc[t] - cnt[t];
    __syncthreads();
    for (int e = e0 + t; e < e1; e += 256) {
        unsigned pk = part[e];
        unsigned p = atomicAdd(&cur[pk >> 20], 1u);
        csr[p] = (int)(pk & 0xFFFFFu);
    }
}

// ---------------- scans over deg -> row; dinv ----------------
__global__ __launch_bounds__(1024) void scan1_kernel(
    const unsigned* __restrict__ deg, unsigned* __restrict__ row,
    unsigned* __restrict__ bsum, int N) {
    __shared__ unsigned sh[1024];
    int gid = blockIdx.x * 1024 + threadIdx.x;
    int t = threadIdx.x;
    unsigned v = (gid < N) ? deg[gid] : 0u;
    sh[t] = v;
    __syncthreads();
#pragma unroll
    for (int off = 1; off < 1024; off <<= 1) {
        unsigned add = (t >= off) ? sh[t - off] : 0u;
        __syncthreads();
        sh[t] += add;
        __syncthreads();
    }
    if (gid < N) row[gid + 1] = sh[t];
    if (t == 1023) bsum[blockIdx.x] = sh[1023];
}

__global__ __launch_bounds__(1024) void scan2_kernel(unsigned* __restrict__ bsum,
                                                     int NB) {
    __shared__ unsigned sh[1024];
    const int t = threadIdx.x;
    unsigned v = (t < NB) ? bsum[t] : 0u;
    sh[t] = v;
    __syncthreads();
#pragma unroll
    for (int off = 1; off < 1024; off <<= 1) {
        unsigned a = (t >= off) ? sh[t - off] : 0u;
        __syncthreads();
        sh[t] += a;
        __syncthreads();
    }
    if (t < NB) bsum[t] = sh[t] - v;
}

__global__ void scan3_kernel(unsigned* __restrict__ row,
                             const unsigned* __restrict__ bsum,
                             const unsigned* __restrict__ deg,
                             float* __restrict__ dinv, int N) {
    int gid = blockIdx.x * blockDim.x + threadIdx.x;
    if (gid >= N) return;
    row[gid + 1] += bsum[gid >> 10];
    if (gid == 0) row[0] = 0u;
    dinv[gid] = rsqrtf((float)deg[gid] + 1.0f);
}

// ---------------- MFMA GEMM: out_bf16 = (A @ B) * dinv[row] ----------------
// 128xBN tile, K=128 single shot, 16x16x32 bf16 MFMA.
// LDS holds A and B pre-swizzled into fragment order:
//   frag(m-tile mt, kstep ks) element offset = ((mt*4+ks)*16 + m)*4 + q)*8 + j
//   lane L reads 8 contiguous bf16 at m=L&15, q=L>>4  -> one ds_read_b128.
// Layouts (m89-verified): A[m=lane&15][k=q*8+j]; B[k=q*8+j][n=lane&15];
// D row=q*4+reg, col=lane&15.
template <int BN, bool ABF16>
__global__ __launch_bounds__(256) void gemm_mfma(
    const void* __restrict__ Av, const float* __restrict__ B,
    const float* __restrict__ dinv, unsigned short* __restrict__ out, int M) {
    constexpr int NT = BN / 16;          // col tiles (8 or 4)
    __shared__ short sA[16384];          // 8 rowtiles * 4 ks * 512  (32 KB)
    __shared__ short sB[NT * 2048];      // NT ntiles  * 4 ks * 512  (32/16 KB)

    const int t = threadIdx.x;
    const int row0 = blockIdx.x * 128;
    const int w = t >> 6, lane = t & 63;
    const int m = lane & 15, q = lane >> 4;

    // ---- stage A (fp32 or bf16 -> swizzled bf16) ----
    if (ABF16) {
        const unsigned short* A = (const unsigned short*)Av;
        for (int g = t; g < 2048; g += 256) {     // 128*128/8
            int r = g >> 4, k0 = (g & 15) << 3;
            uint4 v = make_uint4(0u, 0u, 0u, 0u);
            if (row0 + r < M) v = *(const uint4*)(A + (size_t)(row0 + r) * 128 + k0);
            int off = ((((r >> 4) * 4 + (k0 >> 5)) * 16 + (r & 15)) * 4 +
                       ((k0 >> 3) & 3)) * 8;
            *(uint4*)(sA + off) = v;
        }
    } else {
        const float* A = (const float*)Av;
        for (int g = t; g < 4096; g += 256) {     // 128*128/4
            int r = g >> 5, k0 = (g & 31) << 2;
            float4 v = make_float4(0.f, 0.f, 0.f, 0.f);
            if (row0 + r < M) v = *(const float4*)(A + (size_t)(row0 + r) * 128 + k0);
            ushort4 u;
            u.x = f2bf(v.x); u.y = f2bf(v.y); u.z = f2bf(v.z); u.w = f2bf(v.w);
            int off = ((((r >> 4) * 4 + (k0 >> 5)) * 16 + (r & 15)) * 4 +
                       ((k0 >> 3) & 3)) * 8 + (k0 & 4);
            *(ushort4*)(sA + off) = u;
        }
    }
    // ---- stage B (fp32 [128][BN] -> swizzled bf16) ----
    for (int g = t; g < BN * 32; g += 256) {
        int n = g % BN, k0 = (g / BN) * 4;        // lanes: consecutive n -> coalesced
        float f0 = B[(size_t)(k0 + 0) * BN + n];
        float f1 = B[(size_t)(k0 + 1) * BN + n];
        float f2 = B[(size_t)(k0 + 2) * BN + n];
        float f3 = B[(size_t)(k0 + 3) * BN + n];
        ushort4 u;
        u.x = f2bf(f0); u.y = f2bf(f1); u.z = f2bf(f2); u.w = f2bf(f3);
        int off = ((((n >> 4) * 4 + (k0 >> 5)) * 16 + (n & 15)) * 4 +
                   ((k0 >> 3) & 3)) * 8 + (k0 & 4);
        *(ushort4*)(sB + off) = u;
    }
    __syncthreads();

    f32x4 acc[2][NT];
#pragma unroll
    for (int lt = 0; lt < 2; lt++)
#pragma unroll
        for (int nt = 0; nt < NT; nt++) acc[lt][nt] = (f32x4){0.f, 0.f, 0.f, 0.f};

    const int fb = (m * 4 + q) * 8;   // lane's frag offset within a 512-el group
#pragma unroll
    for (int ks = 0; ks < 4; ks++) {
        bf16x8 a0 = *(const bf16x8*)(sA + ((w * 2 + 0) * 4 + ks) * 512 + fb);
        bf16x8 a1 = *(const bf16x8*)(sA + ((w * 2 + 1) * 4 + ks) * 512 + fb);
#pragma unroll
        for (int nt = 0; nt < NT; nt++) {
            bf16x8 b = *(const bf16x8*)(sB + (nt * 4 + ks) * 512 + fb);
            acc[0][nt] = __builtin_amdgcn_mfma_f32_16x16x32_bf16(a0, b, acc[0][nt], 0, 0, 0);
            acc[1][nt] = __builtin_amdgcn_mfma_f32_16x16x32_bf16(a1, b, acc[1][nt], 0, 0, 0);
        }
    }

    // ---- epilogue: scale by dinv, store bf16 ----
#pragma unroll
    for (int lt = 0; lt < 2; lt++) {
#pragma unroll
        for (int r = 0; r < 4; r++) {
            int row = row0 + w * 32 + lt * 16 + q * 4 + r;
            if (row < M) {
                float s = dinv[row];
#pragma unroll
                for (int nt = 0; nt < NT; nt++)
                    out[(size_t)row * BN + nt * 16 + m] = f2bf(acc[lt][nt][r] * s);
            }
        }
    }
}

// ---------------- gather aggregation + fused epilogue (bf16 table) ---------
// out[i] = maybe_relu( dinv[i] * ( hs[i] + sum_{e in row i} hs[csr[e]] ) + b )
// Lane owns 8 channels (uint4 = 16 B of bf16). LPN = C/8 lanes per node.
template <int C, bool RELU, bool OUTBF>
__global__ __launch_bounds__(256) void agg_kernel(
    const int* __restrict__ csr, const unsigned* __restrict__ row,
    const unsigned short* __restrict__ hsb, const float* __restrict__ dinv,
    const float* __restrict__ bias, void* __restrict__ outv, int N) {
    constexpr int LPN = C / 8;  // lanes per node (16 or 8)
    const int tid = blockIdx.x * 256 + threadIdx.x;
    const int i = tid / LPN;
    const int l = tid % LPN;
    if (i >= N) return;

    const int co = 8 * l;
    float s0 = 0.f, s1 = 0.f, s2 = 0.f, s3 = 0.f,
          s4 = 0.f, s5 = 0.f, s6 = 0.f, s7 = 0.f;
    {
        uint4 u = *(const uint4*)(hsb + (size_t)i * C + co);   // self
        s0 += __uint_as_float(u.x << 16); s1 += __uint_as_float(u.x & 0xffff0000u);
        s2 += __uint_as_float(u.y << 16); s3 += __uint_as_float(u.y & 0xffff0000u);
        s4 += __uint_as_float(u.z << 16); s5 += __uint_as_float(u.z & 0xffff0000u);
        s6 += __uint_as_float(u.w << 16); s7 += __uint_as_float(u.w & 0xffff0000u);
    }

    const int rs = (int)row[i], re = (int)row[i + 1];
    for (int e0 = rs; e0 < re; e0 += LPN) {
        int idx = (e0 + l < re) ? csr[e0 + l] : 0;
        const int cnt = min(LPN, re - e0);
#pragma unroll 4
        for (int j = 0; j < cnt; j++) {
            int s = __shfl(idx, j, LPN);
            uint4 u = *(const uint4*)(hsb + (size_t)s * C + co);
            s0 += __uint_as_float(u.x << 16); s1 += __uint_as_float(u.x & 0xffff0000u);
            s2 += __uint_as_float(u.y << 16); s3 += __uint_as_float(u.y & 0xffff0000u);
            s4 += __uint_as_float(u.z << 16); s5 += __uint_as_float(u.z & 0xffff0000u);
            s6 += __uint_as_float(u.w << 16); s7 += __uint_as_float(u.w & 0xffff0000u);
        }
    }

    const float sc = dinv[i];
    const float4 ba = *(const float4*)(bias + co);
    const float4 bb = *(const float4*)(bias + co + 4);
    float o0 = s0 * sc + ba.x, o1 = s1 * sc + ba.y;
    float o2 = s2 * sc + ba.z, o3 = s3 * sc + ba.w;
    float o4 = s4 * sc + bb.x, o5 = s5 * sc + bb.y;
    float o6 = s6 * sc + bb.z, o7 = s7 * sc + bb.w;
    if (RELU) {
        o0 = fmaxf(o0, 0.f); o1 = fmaxf(o1, 0.f); o2 = fmaxf(o2, 0.f);
        o3 = fmaxf(o3, 0.f); o4 = fmaxf(o4, 0.f); o5 = fmaxf(o5, 0.f);
        o6 = fmaxf(o6, 0.f); o7 = fmaxf(o7, 0.f);
    }
    if (OUTBF) {
        uint4 u;
        u.x = (unsigned)f2bf(o0) | ((unsigned)f2bf(o1) << 16);
        u.y = (unsigned)f2bf(o2) | ((unsigned)f2bf(o3) << 16);
        u.z = (unsigned)f2bf(o4) | ((unsigned)f2bf(o5) << 16);
        u.w = (unsigned)f2bf(o6) | ((unsigned)f2bf(o7) << 16);
        *(uint4*)((unsigned short*)outv + (size_t)i * C + co) = u;
    } else {
        float4 a = make_float4(o0, o1, o2, o3);
        float4 b = make_float4(o4, o5, o6, o7);
        *(float4*)((float*)outv + (size_t)i * C + co) = a;
        *(float4*)((float*)outv + (size_t)i * C + co + 4) = b;
    }
}

// ---------------- launch ----------------
extern "C" void kernel_launch(void* const* d_in, const int* in_sizes, int n_in,
                              void* d_out, int out_size, void* d_ws,
                              size_t ws_size, hipStream_t stream) {
    const float* x  = (const float*)d_in[0];
    const float* W1 = (const float*)d_in[1];
    const float* b1 = (const float*)d_in[2];
    const float* W2 = (const float*)d_in[3];
    const float* b2 = (const float*)d_in[4];
    const unsigned* ew = (const unsigned*)d_in[5];
    const int E = in_sizes[5] / 2;        // 1,600,000
    const int N = in_sizes[0] / 128;      // 100,000
    const int NB = (N + 1023) >> 10;
    const int nbuck = (N + BWIDTH - 1) >> BSHIFT;   // 782

    char* ws = (char*)d_ws;
    unsigned* flag = (unsigned*)(ws + OFF_FLAG);
    unsigned* deg  = (unsigned*)(ws + OFF_DEG);
    unsigned* row  = (unsigned*)(ws + OFF_ROW);
    unsigned* bsum = (unsigned*)(ws + OFF_BSUM);
    unsigned* ccnt = (unsigned*)(ws + OFF_CCNT);
    unsigned* coff = (unsigned*)(ws + OFF_COFF);
    float* dinv    = (float*)(ws + OFF_DINV);
    int* csr       = (int*)(ws + OFF_CSR);
    unsigned short* hs1  = (unsigned short*)(ws + OFF_HS1);
    unsigned short* out1 = (unsigned short*)(ws + OFF_OUT1);
    unsigned short* hs2  = (unsigned short*)(ws + OFF_HS2);
    unsigned* h2   = (unsigned*)(ws + OFF_H2);
    unsigned* part = (unsigned*)(ws + OFF_HS1);  // dead before gemm1 writes hs1

    hipMemsetAsync(flag, 0, 4, stream);
    hipMemsetAsync(ccnt, 0, (size_t)(nbuck + 1) * 4, stream);

    // ---- CSR build ----
    detect_kernel<<<16, 256, 0, stream>>>(ew, flag);
    coarse_hist_kernel<<<NPART, 1024, 0, stream>>>(ew, flag, ccnt, h2, E, nbuck);
    coarse_scan_kernel<<<1, 1024, 0, stream>>>(ccnt, coff, nbuck);
    off2d_kernel<<<nbuck, NPART, 0, stream>>>(h2, coff);
    partition_kernel<<<NPART, 1024, 0, stream>>>(ew, flag, h2, part, E, nbuck);
    bucket_csr_kernel<<<nbuck, 256, 0, stream>>>(part, coff, deg, csr, N);
    scan1_kernel<<<NB, 1024, 0, stream>>>(deg, row, bsum, N);
    scan2_kernel<<<1, 1024, 0, stream>>>(bsum, NB);
    scan3_kernel<<<(N + 255) / 256, 256, 0, stream>>>(row, bsum, deg, dinv, N);

    // ---- layer 1 (C=128) ----
    gemm_mfma<128, false><<<(N + 127) / 128, 256, 0, stream>>>(x, W1, dinv, hs1, N);
    agg_kernel<128, true, true><<<(N * 16 + 255) / 256, 256, 0, stream>>>(
        csr, row, hs1, dinv, b1, out1, N);

    // ---- layer 2 (C=64) ----
    gemm_mfma<64, true><<<(N + 127) / 128, 256, 0, stream>>>(out1, W2, dinv, hs2, N);
    agg_kernel<64, false, false><<<(N * 8 + 255) / 256, 256, 0, stream>>>(
        csr, row, hs2, dinv, b2, d_out, N);
}